// Round 1
// 229.776 us; speedup vs baseline: 1.0017x; 1.0017x over previous
//
#include <hip/hip_runtime.h>
#include <hip/hip_bf16.h>

typedef __bf16 bf16;
typedef __bf16 bf16x4 __attribute__((ext_vector_type(4)));
typedef __bf16 bf16x8 __attribute__((ext_vector_type(8)));
typedef float f32x4 __attribute__((ext_vector_type(4)));

// B=4, T=8, L=512, D=512, H=8, E=64.  BT=32, BTH=256, M=BT*L=16384.

#if __has_builtin(__builtin_amdgcn_exp2f)
#define EXP2(x) __builtin_amdgcn_exp2f(x)
#else
#define EXP2(x) exp2f(x)
#endif

static __device__ __forceinline__ f32x4 mfma16(bf16x4 a, bf16x4 b, f32x4 c) {
#if __has_builtin(__builtin_amdgcn_mfma_f32_16x16x16bf16_1k)
    return __builtin_amdgcn_mfma_f32_16x16x16bf16_1k(a, b, c, 0, 0, 0);
#else
    asm("v_mfma_f32_16x16x16_bf16 %0, %1, %2, %0" : "+v"(c) : "v"(a), "v"(b));
    return c;
#endif
}

// ---------------------------------------------------------------------------
// prep: z<3: W[d][n] fp32 -> Wt[z][n][d] bf16 (64x64 LDS tile transpose)
//       z==3: mask (512,512) f32 -> Mp bf16 in attn per-lane coalesced order:
//             Mp[((qg*8+c)*4+ns)*256 + (quad*16+lc)*4 + r]
//               = mask[qg*16+lc][c*64 + ns*16 + quad*4 + r]
// ---------------------------------------------------------------------------
__global__ __launch_bounds__(256) void prep_kernel(const float* __restrict__ W0,
                                                   const float* __restrict__ W1,
                                                   const float* __restrict__ W2,
                                                   const float* __restrict__ maskf,
                                                   bf16* __restrict__ Wt,
                                                   bf16* __restrict__ Mp) {
    if (blockIdx.z == 3) {
        const int bid = blockIdx.y * 8 + blockIdx.x;  // 0..63
        const int t0 = bid * 256 + threadIdx.x;
        const float4* m4 = (const float4*)maskf;
#pragma unroll
        for (int j = 0; j < 4; ++j) {
            int idx = t0 + j * 16384;   // float4 index 0..65535 (coalesced read)
            int q = idx >> 7;           // row
            int sc = idx & 127;         // float4-col; s = sc*4
            int cc = sc >> 4;           // chunk 0..7
            int ns = (sc >> 2) & 3;
            int qd = sc & 3;            // quad
            float4 v = m4[idx];
            bf16x4 o;
            o[0] = (bf16)v.x; o[1] = (bf16)v.y; o[2] = (bf16)v.z; o[3] = (bf16)v.w;
            size_t off = ((((size_t)(q >> 4) * 8 + cc) * 4 + ns) * 4 + qd) * 64 +
                         (q & 15) * 4;
            *(bf16x4*)&Mp[off] = o;
        }
        return;
    }
    __shared__ float t[64][65];
    const float* W = (blockIdx.z == 0) ? W0 : (blockIdx.z == 1) ? W1 : W2;
    bf16* O = Wt + (size_t)blockIdx.z * 512 * 512;
    const int d0 = blockIdx.x * 64, n0 = blockIdx.y * 64;
    {
        int nl = threadIdx.x & 63, dg = threadIdx.x >> 6;
#pragma unroll
        for (int j = 0; j < 16; ++j) {
            int dl = dg + j * 4;
            t[nl][dl] = W[(size_t)(d0 + dl) * 512 + n0 + nl];
        }
    }
    __syncthreads();
    {
        int dl = threadIdx.x & 63, ng = threadIdx.x >> 6;
#pragma unroll
        for (int j = 0; j < 16; ++j) {
            int nl = ng + j * 4;
            O[(size_t)(n0 + nl) * 512 + d0 + dl] = (bf16)t[nl][dl];
        }
    }
}

// ---------------------------------------------------------------------------
// proj: C[m,n] = sum_k X[m,k]*W[k,n], 3 GEMMs in one dispatch (z).
// 128x128 tile, BK=64, 4 waves 2x2, register double-buffered staging.
// XCD-aware swizzle: the 4 n-tiles of one m-tile run adjacently on one XCD so
// the fp32 X rows are fetched into that XCD's L2 once and reused 4x.
// ---------------------------------------------------------------------------
__global__ __launch_bounds__(256) void proj_kernel(
    const float* __restrict__ Xq, const float* __restrict__ Xk,
    const float* __restrict__ Xv, const bf16* __restrict__ Wt,
    bf16* __restrict__ Qw, bf16* __restrict__ Kw, bf16* __restrict__ Vt) {
    __shared__ __align__(16) bf16 smem[18432];  // la+lb; reused as C-tile
    bf16* la = smem;              // [m][k] 128x72
    bf16* lb = smem + 128 * 72;   // [n][k] 128x72

    const float* X = (blockIdx.z == 0) ? Xq : (blockIdx.z == 1) ? Xk : Xv;
    const bf16* W  = Wt + (size_t)blockIdx.z * 512 * 512;
    bf16* Out      = (blockIdx.z == 0) ? Qw : (blockIdx.z == 1) ? Kw : Vt;

    const int tid = threadIdx.x, wave = tid >> 6, lane = tid & 63;
    const int quad = lane >> 4, lc = lane & 15;
    const int wm = wave & 1, wn = wave >> 1;
    // XCD-aware swizzle: bid = x + y*128 (dispatch order).  xcd = bid&7.
    const int bid = blockIdx.x + (blockIdx.y << 7);  // 0..511
    const int jj = bid >> 3;
    const int yy = jj & 3;                // n-tile (fastest within an XCD)
    const int xt = (bid & 7) * 16 + (jj >> 2);  // m-tile
    const int m0 = xt * 128, n0 = yy * 128;

    f32x4 acc[4][4];
#pragma unroll
    for (int ms = 0; ms < 4; ++ms)
#pragma unroll
        for (int ns = 0; ns < 4; ++ns) acc[ms][ns] = (f32x4){0.f, 0.f, 0.f, 0.f};

    const int ar = tid >> 4, ac = tid & 15;
    const int br = tid >> 3, bc = tid & 7;

    float4 xr[8];
    bf16x8 wr[4];
#pragma unroll
    for (int i = 0; i < 8; ++i)
        xr[i] = *(const float4*)&X[(size_t)(m0 + ar + i * 16) * 512 + ac * 4];
#pragma unroll
    for (int i = 0; i < 4; ++i)
        wr[i] = *(const bf16x8*)&W[(size_t)(n0 + br + i * 32) * 512 + bc * 8];

    for (int kb = 0; kb < 512; kb += 64) {
        __syncthreads();
#pragma unroll
        for (int i = 0; i < 8; ++i) {
            float4 x = xr[i];
            bf16x4 p;
            p[0] = (bf16)x.x; p[1] = (bf16)x.y; p[2] = (bf16)x.z; p[3] = (bf16)x.w;
            *(bf16x4*)&la[(ar + i * 16) * 72 + ac * 4] = p;
        }
#pragma unroll
        for (int i = 0; i < 4; ++i)
            *(bf16x8*)&lb[(br + i * 32) * 72 + bc * 8] = wr[i];
        __syncthreads();
        if (kb < 448) {
            int kn = kb + 64;
#pragma unroll
            for (int i = 0; i < 8; ++i)
                xr[i] = *(const float4*)&X[(size_t)(m0 + ar + i * 16) * 512 + kn + ac * 4];
#pragma unroll
            for (int i = 0; i < 4; ++i)
                wr[i] = *(const bf16x8*)&W[(size_t)(n0 + br + i * 32) * 512 + kn + bc * 8];
        }
#pragma unroll
        for (int kk = 0; kk < 2; ++kk) {
            bf16x8 af[4], bfr[4];
#pragma unroll
            for (int ms = 0; ms < 4; ++ms)
                af[ms] = *(bf16x8*)&la[(wm * 64 + ms * 16 + lc) * 72 + kk * 32 + quad * 8];
#pragma unroll
            for (int ns = 0; ns < 4; ++ns)
                bfr[ns] = *(bf16x8*)&lb[(wn * 64 + ns * 16 + lc) * 72 + kk * 32 + quad * 8];
#pragma unroll
            for (int ms = 0; ms < 4; ++ms)
#pragma unroll
                for (int ns = 0; ns < 4; ++ns)
                    acc[ms][ns] = __builtin_amdgcn_mfma_f32_16x16x32_bf16(
                        af[ms], bfr[ns], acc[ms][ns], 0, 0, 0);
        }
    }
    // --- epilogue ---
    __syncthreads();
    bf16* lds_c = smem;  // z<2: [m][n] 128x136 ; z==2: [n][m] 128x136
    if (blockIdx.z != 2) {
#pragma unroll
        for (int ms = 0; ms < 4; ++ms)
#pragma unroll
            for (int ns = 0; ns < 4; ++ns)
#pragma unroll
                for (int r = 0; r < 4; ++r)
                    lds_c[(wm * 64 + ms * 16 + quad * 4 + r) * 136 +
                          wn * 64 + ns * 16 + lc] = (bf16)acc[ms][ns][r];
    } else {
#pragma unroll
        for (int ms = 0; ms < 4; ++ms)
#pragma unroll
            for (int ns = 0; ns < 4; ++ns)
#pragma unroll
                for (int r = 0; r < 4; ++r)
                    lds_c[(wn * 64 + ns * 16 + lc) * 136 +
                          wm * 64 + ms * 16 + quad * 4 + r] = (bf16)acc[ms][ns][r];
    }
    __syncthreads();
    const int bt = m0 >> 9, l0 = m0 & 511;
    if (blockIdx.z != 2) {
        const int ec = tid & 7, rg = tid >> 3;
#pragma unroll
        for (int hc = 0; hc < 2; ++hc) {
            int h = (n0 >> 6) + hc;
#pragma unroll
            for (int p = 0; p < 4; ++p) {
                int row = rg + p * 32;
                bf16x8 v = *(bf16x8*)&lds_c[row * 136 + hc * 64 + ec * 8];
                *(bf16x8*)&Out[(((size_t)bt * 8 + h) * 512 + l0 + row) * 64 + ec * 8] = v;
            }
        }
    } else {
        const int rowp = lane >> 2, cc = lane & 3;
#pragma unroll
        for (int pr = 0; pr < 2; ++pr) {
            int row = wave * 32 + pr * 16 + rowp;  // n_local 0..127
            int h = (n0 >> 6) + (row >> 6);
            int e = row & 63;
            bf16* dst = Out + (((size_t)bt * 8 + h) * 64 + e) * 512 + l0;
#pragma unroll
            for (int pc = 0; pc < 4; ++pc) {
                int mc = cc + pc * 4;
                *(bf16x8*)&dst[mc * 8] = *(bf16x8*)&lds_c[row * 136 + mc * 8];
            }
        }
    }
}

// ---------------------------------------------------------------------------
// attn v8: wave owns 32 q-rows (2 q-tiles). S^T orientation; fixed-max
// softmax.  Changes vs v7:
//  - mask pre-transformed (prep z=3) to bf16 in per-lane order -> every mask
//    load is base + lane*8 (coalesced 512B/wave-instr, half the bytes)
//  - PV uses v_mfma 16x16x16: softmaxed S^T fragments feed PV's A-operand
//    directly in registers (A k-layout quad*4+j == C/D row-layout quad*4+r).
//    lds_p deleted, no P write/read latency.
//  - K/V LDS double-buffered: ONE barrier per chunk, stage writes overlap
//    compute, global K/V prefetch depth 2.
//  - exp2 with folded tau*scale*log2e constants.
// grid 1024 (4 blocks/CU, LDS 36.9KB): bth = b & 255, qquad = b >> 8.
// ---------------------------------------------------------------------------
__global__ __launch_bounds__(256, 4) void attn_kernel(
    const bf16* __restrict__ Qw, const bf16* __restrict__ Kw,
    const bf16* __restrict__ Vt, const bf16* __restrict__ Mp,
    const float* __restrict__ w_head, const float* __restrict__ tau,
    const float* __restrict__ delta, float* __restrict__ out) {
    __shared__ __align__(16) bf16 lds_k[2][64 * 72];   // [s][e], pad 8
    __shared__ __align__(16) bf16 lds_vt[2][64 * 72];  // [e][s], pad 8

    const int tid  = threadIdx.x;
    const int wave = tid >> 6;
    const int lane = tid & 63;
    const int quad = lane >> 4;
    const int lc   = lane & 15;
    const int b    = blockIdx.x;
    const int bth  = b & 255;
    const int qquad = b >> 8;  // 0..3
    const int bt   = bth >> 3;
    const int h    = bth & 7;

    const bf16* Qh  = Qw + (size_t)bth * (512 * 64);
    const bf16* Kh  = Kw + (size_t)bth * (512 * 64);
    const bf16* VtH = Vt + (size_t)bth * (512 * 64);  // [e][s]

    const float L2E = 1.4426950408889634f;
    const float ts = tau[0] * 0.125f * L2E;    // tau * 1/sqrt(64) * log2(e)
    const float ds = delta[0] * 0.125f * L2E;
    const float wh = w_head[h];

    const int q0 = qquad * 128 + wave * 32;  // tiles at q0 and q0+16
    const size_t mbA = (size_t)(q0 >> 4) * 8192 + lane * 4;  // mask base, tile A
    const size_t mbB = mbA + 8192;                           // tile B (qg+1)

    // Q fragments (B-operand) for both tiles
    bf16x8 qfA[2], qfB[2];
#pragma unroll
    for (int kk = 0; kk < 2; ++kk) {
        qfA[kk] = *(const bf16x8*)&Qh[(size_t)(q0 + lc) * 64 + kk * 32 + quad * 8];
        qfB[kk] = *(const bf16x8*)&Qh[(size_t)(q0 + 16 + lc) * 64 + kk * 32 + quad * 8];
    }

    f32x4 oA[4], oB[4];
#pragma unroll
    for (int ns = 0; ns < 4; ++ns) {
        oA[ns] = (f32x4){0.f, 0.f, 0.f, 0.f};
        oB[ns] = (f32x4){0.f, 0.f, 0.f, 0.f};
    }
    float lA = 0.f, lB = 0.f;  // per-lane partial sums, q = lc (+16)

    const int srow = tid >> 3, scc = tid & 7;
    bf16x8 kr[2], vr[2];
    // chunk 0 load + stage into buf0 (no barrier needed: disjoint writes)
    kr[0] = *(const bf16x8*)&Kh[(size_t)srow * 64 + scc * 8];
    kr[1] = *(const bf16x8*)&Kh[(size_t)(srow + 32) * 64 + scc * 8];
    vr[0] = *(const bf16x8*)&VtH[(size_t)srow * 512 + scc * 8];
    vr[1] = *(const bf16x8*)&VtH[(size_t)(srow + 32) * 512 + scc * 8];
    *(bf16x8*)&lds_k[0][srow * 72 + scc * 8] = kr[0];
    *(bf16x8*)&lds_k[0][(srow + 32) * 72 + scc * 8] = kr[1];
    *(bf16x8*)&lds_vt[0][srow * 72 + scc * 8] = vr[0];
    *(bf16x8*)&lds_vt[0][(srow + 32) * 72 + scc * 8] = vr[1];
    // prefetch chunk 1
    kr[0] = *(const bf16x8*)&Kh[(size_t)(64 + srow) * 64 + scc * 8];
    kr[1] = *(const bf16x8*)&Kh[(size_t)(64 + srow + 32) * 64 + scc * 8];
    vr[0] = *(const bf16x8*)&VtH[(size_t)srow * 512 + 64 + scc * 8];
    vr[1] = *(const bf16x8*)&VtH[(size_t)(srow + 32) * 512 + 64 + scc * 8];

    for (int c = 0; c < 8; ++c) {
        const int buf = c & 1;
        __syncthreads();  // buf[c&1] staged (prologue or end of body c-1)
        // coalesced bf16 mask loads, issued early (consumed after QK)
        bf16x4 mA[4], mB[4];
        {
            const size_t mc = mbA + (size_t)c * 1024;
            const size_t md = mbB + (size_t)c * 1024;
#pragma unroll
            for (int ns = 0; ns < 4; ++ns) {
                mA[ns] = *(const bf16x4*)&Mp[mc + ns * 256];
                mB[ns] = *(const bf16x4*)&Mp[md + ns * 256];
            }
        }
        // S^T = K . Q^T for both q-tiles (K-frag read shared)
        f32x4 stA[4], stB[4];
#pragma unroll
        for (int ns = 0; ns < 4; ++ns) {
            stA[ns] = (f32x4){0.f, 0.f, 0.f, 0.f};
            stB[ns] = (f32x4){0.f, 0.f, 0.f, 0.f};
        }
#pragma unroll
        for (int kk = 0; kk < 2; ++kk)
#pragma unroll
            for (int ns = 0; ns < 4; ++ns) {
                bf16x8 ka = *(bf16x8*)&lds_k[buf][(ns * 16 + lc) * 72 + kk * 32 + quad * 8];
                stA[ns] = __builtin_amdgcn_mfma_f32_16x16x32_bf16(ka, qfA[kk], stA[ns], 0, 0, 0);
                stB[ns] = __builtin_amdgcn_mfma_f32_16x16x32_bf16(ka, qfB[kk], stB[ns], 0, 0, 0);
            }
        // stage chunk c+1 into other buffer; prefetch chunk c+2
        if (c < 7) {
            const int nb = buf ^ 1;
            *(bf16x8*)&lds_k[nb][srow * 72 + scc * 8] = kr[0];
            *(bf16x8*)&lds_k[nb][(srow + 32) * 72 + scc * 8] = kr[1];
            *(bf16x8*)&lds_vt[nb][srow * 72 + scc * 8] = vr[0];
            *(bf16x8*)&lds_vt[nb][(srow + 32) * 72 + scc * 8] = vr[1];
            if (c < 6) {
                const int s0n = (c + 2) * 64;
                kr[0] = *(const bf16x8*)&Kh[(size_t)(s0n + srow) * 64 + scc * 8];
                kr[1] = *(const bf16x8*)&Kh[(size_t)(s0n + srow + 32) * 64 + scc * 8];
                vr[0] = *(const bf16x8*)&VtH[(size_t)srow * 512 + s0n + scc * 8];
                vr[1] = *(const bf16x8*)&VtH[(size_t)(srow + 32) * 512 + s0n + scc * 8];
            }
        }
        // softmax (fixed-max): p = exp2((st*ts + ds) * m) -> PV A-fragments
        bf16x4 paA[4], paB[4];
#pragma unroll
        for (int ns = 0; ns < 4; ++ns) {
#pragma unroll
            for (int r = 0; r < 4; ++r) {
                float eA = (stA[ns][r] * ts + ds) * (float)mA[ns][r];
                float eB = (stB[ns][r] * ts + ds) * (float)mB[ns][r];
                float pA = EXP2(eA);
                float pB = EXP2(eB);
                lA += pA; lB += pB;
                paA[ns][r] = (bf16)pA;
                paB[ns][r] = (bf16)pB;
            }
        }
        // O += P . V via 16x16x16 (A-frag = paA[ks] directly; V-frag shared)
#pragma unroll
        for (int ks = 0; ks < 4; ++ks)
#pragma unroll
            for (int ns = 0; ns < 4; ++ns) {
                bf16x4 vv = *(bf16x4*)&lds_vt[buf][(ns * 16 + lc) * 72 + ks * 16 + quad * 4];
                oA[ns] = mfma16(paA[ks], vv, oA[ns]);
                oB[ns] = mfma16(paB[ks], vv, oB[ns]);
            }
    }
    // epilogue: reduce l across quads, normalize, accumulate heads
    lA += __shfl_xor(lA, 16, 64);
    lA += __shfl_xor(lA, 32, 64);
    lB += __shfl_xor(lB, 16, 64);
    lB += __shfl_xor(lB, 32, 64);
#pragma unroll
    for (int r = 0; r < 4; ++r) {
        float lrA = __shfl(lA, quad * 4 + r, 64);
        float lrB = __shfl(lB, quad * 4 + r, 64);
        float ivA = wh / lrA, ivB = wh / lrB;
        int qqA = q0 + quad * 4 + r;
        int qqB = q0 + 16 + quad * 4 + r;
#pragma unroll
        for (int ns = 0; ns < 4; ++ns) {
            int e = ns * 16 + lc;
            atomicAdd(&out[((size_t)bt * 512 + qqA) * 64 + e], oA[ns][r] * ivA);
            atomicAdd(&out[((size_t)bt * 512 + qqB) * 64 + e], oB[ns][r] * ivB);
        }
    }
}

// ---------------------------------------------------------------------------
extern "C" void kernel_launch(void* const* d_in, const int* in_sizes, int n_in,
                              void* d_out, int out_size, void* d_ws, size_t ws_size,
                              hipStream_t stream) {
    const float* queries = (const float*)d_in[0];
    const float* keys    = (const float*)d_in[1];
    const float* values  = (const float*)d_in[2];
    const float* mask    = (const float*)d_in[3];
    const float* Wq      = (const float*)d_in[4];
    const float* Wk      = (const float*)d_in[5];
    const float* Wv      = (const float*)d_in[6];
    const float* w_head  = (const float*)d_in[7];
    const float* tau     = (const float*)d_in[8];
    const float* delta   = (const float*)d_in[9];

    char* ws = (char*)d_ws;
    bf16* Qw = (bf16*)(ws);                    // 16,777,216 B
    bf16* Kw = (bf16*)(ws + 16777216ull);      // 16,777,216 B
    bf16* Vt = (bf16*)(ws + 33554432ull);      // 16,777,216 B (V^T [bth][e][s])
    bf16* Wt = (bf16*)(ws + 50331648ull);      //  1,572,864 B
    bf16* Mp = (bf16*)(ws + 51904512ull);      //    524,288 B (mask, attn order)

    hipMemsetAsync(d_out, 0, (size_t)out_size * sizeof(float), stream);

    prep_kernel<<<dim3(8, 8, 4), 256, 0, stream>>>(Wq, Wk, Wv, mask, Wt, Mp);

    proj_kernel<<<dim3(128, 4, 3), 256, 0, stream>>>(queries, keys, values, Wt,
                                                     Qw, Kw, Vt);

    attn_kernel<<<1024, 256, 0, stream>>>(Qw, Kw, Vt, Mp, w_head, tau, delta,
                                          (float*)d_out);
}

// Round 2
// 224.628 us; speedup vs baseline: 1.0247x; 1.0229x over previous
//
#include <hip/hip_runtime.h>
#include <hip/hip_bf16.h>

typedef __bf16 bf16;
typedef __bf16 bf16x4 __attribute__((ext_vector_type(4)));
typedef __bf16 bf16x8 __attribute__((ext_vector_type(8)));
typedef float f32x4 __attribute__((ext_vector_type(4)));
typedef _Float16 half4 __attribute__((ext_vector_type(4)));

// B=4, T=8, L=512, D=512, H=8, E=64.  BT=32, BTH=256, M=BT*L=16384.

#if __has_builtin(__builtin_amdgcn_exp2f)
#define EXP2(x) __builtin_amdgcn_exp2f(x)
#else
#define EXP2(x) exp2f(x)
#endif

static __device__ __forceinline__ f32x4 mfma16(bf16x4 a, bf16x4 b, f32x4 c) {
#if __has_builtin(__builtin_amdgcn_mfma_f32_16x16x16bf16_1k)
    return __builtin_amdgcn_mfma_f32_16x16x16bf16_1k(a, b, c, 0, 0, 0);
#else
    asm("v_mfma_f32_16x16x16_bf16 %0, %1, %2, %0" : "+v"(c) : "v"(a), "v"(b));
    return c;
#endif
}

// ---------------------------------------------------------------------------
// prep: z<3: W[d][n] fp32 -> Wt[z][n][d] bf16 (64x64 LDS tile transpose)
//       z==3: mask (512,512) f32 -> Mp bf16 in attn per-lane coalesced order:
//             Mp[((qg*8+c)*4+ns)*256 + (quad*16+lc)*4 + r]
//               = mask[qg*16+lc][c*64 + ns*16 + quad*4 + r]
// ---------------------------------------------------------------------------
__global__ __launch_bounds__(256) void prep_kernel(const float* __restrict__ W0,
                                                   const float* __restrict__ W1,
                                                   const float* __restrict__ W2,
                                                   const float* __restrict__ maskf,
                                                   bf16* __restrict__ Wt,
                                                   bf16* __restrict__ Mp) {
    if (blockIdx.z == 3) {
        const int bid = blockIdx.y * 8 + blockIdx.x;  // 0..63
        const int t0 = bid * 256 + threadIdx.x;
        const float4* m4 = (const float4*)maskf;
#pragma unroll
        for (int j = 0; j < 4; ++j) {
            int idx = t0 + j * 16384;   // float4 index 0..65535 (coalesced read)
            int q = idx >> 7;           // row
            int sc = idx & 127;         // float4-col; s = sc*4
            int cc = sc >> 4;           // chunk 0..7
            int ns = (sc >> 2) & 3;
            int qd = sc & 3;            // quad
            float4 v = m4[idx];
            bf16x4 o;
            o[0] = (bf16)v.x; o[1] = (bf16)v.y; o[2] = (bf16)v.z; o[3] = (bf16)v.w;
            size_t off = ((((size_t)(q >> 4) * 8 + cc) * 4 + ns) * 4 + qd) * 64 +
                         (q & 15) * 4;
            *(bf16x4*)&Mp[off] = o;
        }
        return;
    }
    __shared__ float t[64][65];
    const float* W = (blockIdx.z == 0) ? W0 : (blockIdx.z == 1) ? W1 : W2;
    bf16* O = Wt + (size_t)blockIdx.z * 512 * 512;
    const int d0 = blockIdx.x * 64, n0 = blockIdx.y * 64;
    {
        int nl = threadIdx.x & 63, dg = threadIdx.x >> 6;
#pragma unroll
        for (int j = 0; j < 16; ++j) {
            int dl = dg + j * 4;
            t[nl][dl] = W[(size_t)(d0 + dl) * 512 + n0 + nl];
        }
    }
    __syncthreads();
    {
        int dl = threadIdx.x & 63, ng = threadIdx.x >> 6;
#pragma unroll
        for (int j = 0; j < 16; ++j) {
            int nl = ng + j * 4;
            O[(size_t)(n0 + nl) * 512 + d0 + dl] = (bf16)t[nl][dl];
        }
    }
}

// ---------------------------------------------------------------------------
// proj: C[m,n] = sum_k X[m,k]*W[k,n], 3 GEMMs in one dispatch (z).
// 128x128 tile, BK=64, 4 waves 2x2, register double-buffered staging.
// XCD-aware swizzle: the 4 n-tiles of one m-tile run adjacently on one XCD.
// ---------------------------------------------------------------------------
__global__ __launch_bounds__(256) void proj_kernel(
    const float* __restrict__ Xq, const float* __restrict__ Xk,
    const float* __restrict__ Xv, const bf16* __restrict__ Wt,
    bf16* __restrict__ Qw, bf16* __restrict__ Kw, bf16* __restrict__ Vt) {
    __shared__ __align__(16) bf16 smem[18432];  // la+lb; reused as C-tile
    bf16* la = smem;              // [m][k] 128x72
    bf16* lb = smem + 128 * 72;   // [n][k] 128x72

    const float* X = (blockIdx.z == 0) ? Xq : (blockIdx.z == 1) ? Xk : Xv;
    const bf16* W  = Wt + (size_t)blockIdx.z * 512 * 512;
    bf16* Out      = (blockIdx.z == 0) ? Qw : (blockIdx.z == 1) ? Kw : Vt;

    const int tid = threadIdx.x, wave = tid >> 6, lane = tid & 63;
    const int quad = lane >> 4, lc = lane & 15;
    const int wm = wave & 1, wn = wave >> 1;
    // XCD-aware swizzle: bid = x + y*128 (dispatch order).  xcd = bid&7.
    const int bid = blockIdx.x + (blockIdx.y << 7);  // 0..511
    const int jj = bid >> 3;
    const int yy = jj & 3;                // n-tile (fastest within an XCD)
    const int xt = (bid & 7) * 16 + (jj >> 2);  // m-tile
    const int m0 = xt * 128, n0 = yy * 128;

    f32x4 acc[4][4];
#pragma unroll
    for (int ms = 0; ms < 4; ++ms)
#pragma unroll
        for (int ns = 0; ns < 4; ++ns) acc[ms][ns] = (f32x4){0.f, 0.f, 0.f, 0.f};

    const int ar = tid >> 4, ac = tid & 15;
    const int br = tid >> 3, bc = tid & 7;

    float4 xr[8];
    bf16x8 wr[4];
#pragma unroll
    for (int i = 0; i < 8; ++i)
        xr[i] = *(const float4*)&X[(size_t)(m0 + ar + i * 16) * 512 + ac * 4];
#pragma unroll
    for (int i = 0; i < 4; ++i)
        wr[i] = *(const bf16x8*)&W[(size_t)(n0 + br + i * 32) * 512 + bc * 8];

    for (int kb = 0; kb < 512; kb += 64) {
        __syncthreads();
#pragma unroll
        for (int i = 0; i < 8; ++i) {
            float4 x = xr[i];
            bf16x4 p;
            p[0] = (bf16)x.x; p[1] = (bf16)x.y; p[2] = (bf16)x.z; p[3] = (bf16)x.w;
            *(bf16x4*)&la[(ar + i * 16) * 72 + ac * 4] = p;
        }
#pragma unroll
        for (int i = 0; i < 4; ++i)
            *(bf16x8*)&lb[(br + i * 32) * 72 + bc * 8] = wr[i];
        __syncthreads();
        if (kb < 448) {
            int kn = kb + 64;
#pragma unroll
            for (int i = 0; i < 8; ++i)
                xr[i] = *(const float4*)&X[(size_t)(m0 + ar + i * 16) * 512 + kn + ac * 4];
#pragma unroll
            for (int i = 0; i < 4; ++i)
                wr[i] = *(const bf16x8*)&W[(size_t)(n0 + br + i * 32) * 512 + kn + bc * 8];
        }
#pragma unroll
        for (int kk = 0; kk < 2; ++kk) {
            bf16x8 af[4], bfr[4];
#pragma unroll
            for (int ms = 0; ms < 4; ++ms)
                af[ms] = *(bf16x8*)&la[(wm * 64 + ms * 16 + lc) * 72 + kk * 32 + quad * 8];
#pragma unroll
            for (int ns = 0; ns < 4; ++ns)
                bfr[ns] = *(bf16x8*)&lb[(wn * 64 + ns * 16 + lc) * 72 + kk * 32 + quad * 8];
#pragma unroll
            for (int ms = 0; ms < 4; ++ms)
#pragma unroll
                for (int ns = 0; ns < 4; ++ns)
                    acc[ms][ns] = __builtin_amdgcn_mfma_f32_16x16x32_bf16(
                        af[ms], bfr[ns], acc[ms][ns], 0, 0, 0);
        }
    }
    // --- epilogue ---
    __syncthreads();
    bf16* lds_c = smem;  // z<2: [m][n] 128x136 ; z==2: [n][m] 128x136
    if (blockIdx.z != 2) {
#pragma unroll
        for (int ms = 0; ms < 4; ++ms)
#pragma unroll
            for (int ns = 0; ns < 4; ++ns)
#pragma unroll
                for (int r = 0; r < 4; ++r)
                    lds_c[(wm * 64 + ms * 16 + quad * 4 + r) * 136 +
                          wn * 64 + ns * 16 + lc] = (bf16)acc[ms][ns][r];
    } else {
#pragma unroll
        for (int ms = 0; ms < 4; ++ms)
#pragma unroll
            for (int ns = 0; ns < 4; ++ns)
#pragma unroll
                for (int r = 0; r < 4; ++r)
                    lds_c[(wn * 64 + ns * 16 + lc) * 136 +
                          wm * 64 + ms * 16 + quad * 4 + r] = (bf16)acc[ms][ns][r];
    }
    __syncthreads();
    const int bt = m0 >> 9, l0 = m0 & 511;
    if (blockIdx.z != 2) {
        const int ec = tid & 7, rg = tid >> 3;
#pragma unroll
        for (int hc = 0; hc < 2; ++hc) {
            int h = (n0 >> 6) + hc;
#pragma unroll
            for (int p = 0; p < 4; ++p) {
                int row = rg + p * 32;
                bf16x8 v = *(bf16x8*)&lds_c[row * 136 + hc * 64 + ec * 8];
                *(bf16x8*)&Out[(((size_t)bt * 8 + h) * 512 + l0 + row) * 64 + ec * 8] = v;
            }
        }
    } else {
        const int rowp = lane >> 2, cc = lane & 3;
#pragma unroll
        for (int pr = 0; pr < 2; ++pr) {
            int row = wave * 32 + pr * 16 + rowp;  // n_local 0..127
            int h = (n0 >> 6) + (row >> 6);
            int e = row & 63;
            bf16* dst = Out + (((size_t)bt * 8 + h) * 64 + e) * 512 + l0;
#pragma unroll
            for (int pc = 0; pc < 4; ++pc) {
                int mc = cc + pc * 4;
                *(bf16x8*)&dst[mc * 8] = *(bf16x8*)&lds_c[row * 136 + mc * 8];
            }
        }
    }
}

// ---------------------------------------------------------------------------
// attn v9: loop identical to v8 (mask pre-layout, in-register P->PV via
// 16x16x16, K/V double-buffer, 1 barrier/chunk).  Epilogue change: the 8.4M
// cross-XCD atomicAdds (8 head-blocks RMW the same out lines -> coherence
// ping-pong, 48MB HBM writes, ~half the kernel time) are replaced by plain
// coalesced stores of normalized, head-weighted partials into workspace
// Opart[bth][q][e]; a reduce kernel sums heads.  mode: 0=atomic fallback
// (ws too small), 1=f32 partials, 2=f16 partials.
// ---------------------------------------------------------------------------
__global__ __launch_bounds__(256, 4) void attn_kernel(
    const bf16* __restrict__ Qw, const bf16* __restrict__ Kw,
    const bf16* __restrict__ Vt, const bf16* __restrict__ Mp,
    const float* __restrict__ w_head, const float* __restrict__ tau,
    const float* __restrict__ delta, float* __restrict__ out,
    void* __restrict__ opart, int mode) {
    __shared__ __align__(16) bf16 lds_k[2][64 * 72];   // [s][e], pad 8
    __shared__ __align__(16) bf16 lds_vt[2][64 * 72];  // [e][s], pad 8

    const int tid  = threadIdx.x;
    const int wave = tid >> 6;
    const int lane = tid & 63;
    const int quad = lane >> 4;
    const int lc   = lane & 15;
    const int b    = blockIdx.x;
    const int bth  = b & 255;
    const int qquad = b >> 8;  // 0..3
    const int bt   = bth >> 3;
    const int h    = bth & 7;

    const bf16* Qh  = Qw + (size_t)bth * (512 * 64);
    const bf16* Kh  = Kw + (size_t)bth * (512 * 64);
    const bf16* VtH = Vt + (size_t)bth * (512 * 64);  // [e][s]

    const float L2E = 1.4426950408889634f;
    const float ts = tau[0] * 0.125f * L2E;    // tau * 1/sqrt(64) * log2(e)
    const float ds = delta[0] * 0.125f * L2E;
    const float wh = w_head[h];

    const int q0 = qquad * 128 + wave * 32;  // tiles at q0 and q0+16
    const size_t mbA = (size_t)(q0 >> 4) * 8192 + lane * 4;  // mask base, tile A
    const size_t mbB = mbA + 8192;                           // tile B (qg+1)

    // Q fragments (B-operand) for both tiles
    bf16x8 qfA[2], qfB[2];
#pragma unroll
    for (int kk = 0; kk < 2; ++kk) {
        qfA[kk] = *(const bf16x8*)&Qh[(size_t)(q0 + lc) * 64 + kk * 32 + quad * 8];
        qfB[kk] = *(const bf16x8*)&Qh[(size_t)(q0 + 16 + lc) * 64 + kk * 32 + quad * 8];
    }

    f32x4 oA[4], oB[4];
#pragma unroll
    for (int ns = 0; ns < 4; ++ns) {
        oA[ns] = (f32x4){0.f, 0.f, 0.f, 0.f};
        oB[ns] = (f32x4){0.f, 0.f, 0.f, 0.f};
    }
    float lA = 0.f, lB = 0.f;  // per-lane partial sums, q = lc (+16)

    const int srow = tid >> 3, scc = tid & 7;
    bf16x8 kr[2], vr[2];
    // chunk 0 load + stage into buf0 (no barrier needed: disjoint writes)
    kr[0] = *(const bf16x8*)&Kh[(size_t)srow * 64 + scc * 8];
    kr[1] = *(const bf16x8*)&Kh[(size_t)(srow + 32) * 64 + scc * 8];
    vr[0] = *(const bf16x8*)&VtH[(size_t)srow * 512 + scc * 8];
    vr[1] = *(const bf16x8*)&VtH[(size_t)(srow + 32) * 512 + scc * 8];
    *(bf16x8*)&lds_k[0][srow * 72 + scc * 8] = kr[0];
    *(bf16x8*)&lds_k[0][(srow + 32) * 72 + scc * 8] = kr[1];
    *(bf16x8*)&lds_vt[0][srow * 72 + scc * 8] = vr[0];
    *(bf16x8*)&lds_vt[0][(srow + 32) * 72 + scc * 8] = vr[1];
    // prefetch chunk 1
    kr[0] = *(const bf16x8*)&Kh[(size_t)(64 + srow) * 64 + scc * 8];
    kr[1] = *(const bf16x8*)&Kh[(size_t)(64 + srow + 32) * 64 + scc * 8];
    vr[0] = *(const bf16x8*)&VtH[(size_t)srow * 512 + 64 + scc * 8];
    vr[1] = *(const bf16x8*)&VtH[(size_t)(srow + 32) * 512 + 64 + scc * 8];

    for (int c = 0; c < 8; ++c) {
        const int buf = c & 1;
        __syncthreads();  // buf[c&1] staged (prologue or end of body c-1)
        // coalesced bf16 mask loads, issued early (consumed after QK)
        bf16x4 mA[4], mB[4];
        {
            const size_t mc = mbA + (size_t)c * 1024;
            const size_t md = mbB + (size_t)c * 1024;
#pragma unroll
            for (int ns = 0; ns < 4; ++ns) {
                mA[ns] = *(const bf16x4*)&Mp[mc + ns * 256];
                mB[ns] = *(const bf16x4*)&Mp[md + ns * 256];
            }
        }
        // S^T = K . Q^T for both q-tiles (K-frag read shared)
        f32x4 stA[4], stB[4];
#pragma unroll
        for (int ns = 0; ns < 4; ++ns) {
            stA[ns] = (f32x4){0.f, 0.f, 0.f, 0.f};
            stB[ns] = (f32x4){0.f, 0.f, 0.f, 0.f};
        }
#pragma unroll
        for (int kk = 0; kk < 2; ++kk)
#pragma unroll
            for (int ns = 0; ns < 4; ++ns) {
                bf16x8 ka = *(bf16x8*)&lds_k[buf][(ns * 16 + lc) * 72 + kk * 32 + quad * 8];
                stA[ns] = __builtin_amdgcn_mfma_f32_16x16x32_bf16(ka, qfA[kk], stA[ns], 0, 0, 0);
                stB[ns] = __builtin_amdgcn_mfma_f32_16x16x32_bf16(ka, qfB[kk], stB[ns], 0, 0, 0);
            }
        // stage chunk c+1 into other buffer; prefetch chunk c+2
        if (c < 7) {
            const int nb = buf ^ 1;
            *(bf16x8*)&lds_k[nb][srow * 72 + scc * 8] = kr[0];
            *(bf16x8*)&lds_k[nb][(srow + 32) * 72 + scc * 8] = kr[1];
            *(bf16x8*)&lds_vt[nb][srow * 72 + scc * 8] = vr[0];
            *(bf16x8*)&lds_vt[nb][(srow + 32) * 72 + scc * 8] = vr[1];
            if (c < 6) {
                const int s0n = (c + 2) * 64;
                kr[0] = *(const bf16x8*)&Kh[(size_t)(s0n + srow) * 64 + scc * 8];
                kr[1] = *(const bf16x8*)&Kh[(size_t)(s0n + srow + 32) * 64 + scc * 8];
                vr[0] = *(const bf16x8*)&VtH[(size_t)srow * 512 + s0n + scc * 8];
                vr[1] = *(const bf16x8*)&VtH[(size_t)(srow + 32) * 512 + s0n + scc * 8];
            }
        }
        // softmax (fixed-max): p = exp2((st*ts + ds) * m) -> PV A-fragments
        bf16x4 paA[4], paB[4];
#pragma unroll
        for (int ns = 0; ns < 4; ++ns) {
#pragma unroll
            for (int r = 0; r < 4; ++r) {
                float eA = (stA[ns][r] * ts + ds) * (float)mA[ns][r];
                float eB = (stB[ns][r] * ts + ds) * (float)mB[ns][r];
                float pA = EXP2(eA);
                float pB = EXP2(eB);
                lA += pA; lB += pB;
                paA[ns][r] = (bf16)pA;
                paB[ns][r] = (bf16)pB;
            }
        }
        // O += P . V via 16x16x16 (A-frag = paA[ks] directly; V-frag shared)
#pragma unroll
        for (int ks = 0; ks < 4; ++ks)
#pragma unroll
            for (int ns = 0; ns < 4; ++ns) {
                bf16x4 vv = *(bf16x4*)&lds_vt[buf][(ns * 16 + lc) * 72 + ks * 16 + quad * 4];
                oA[ns] = mfma16(paA[ks], vv, oA[ns]);
                oB[ns] = mfma16(paB[ks], vv, oB[ns]);
            }
    }
    // epilogue: reduce l across quads, normalize, weight by wh
    lA += __shfl_xor(lA, 16, 64);
    lA += __shfl_xor(lA, 32, 64);
    lB += __shfl_xor(lB, 16, 64);
    lB += __shfl_xor(lB, 32, 64);
#pragma unroll
    for (int r = 0; r < 4; ++r) {
        float lrA = __shfl(lA, quad * 4 + r, 64);
        float lrB = __shfl(lB, quad * 4 + r, 64);
        float ivA = wh / lrA, ivB = wh / lrB;
        int qqA = q0 + quad * 4 + r;
        int qqB = q0 + 16 + quad * 4 + r;
        if (mode == 0) {
#pragma unroll
            for (int ns = 0; ns < 4; ++ns) {
                int e = ns * 16 + lc;
                atomicAdd(&out[((size_t)bt * 512 + qqA) * 64 + e], oA[ns][r] * ivA);
                atomicAdd(&out[((size_t)bt * 512 + qqB) * 64 + e], oB[ns][r] * ivB);
            }
        } else if (mode == 1) {
            float* op = (float*)opart;
#pragma unroll
            for (int ns = 0; ns < 4; ++ns) {
                int e = ns * 16 + lc;
                op[((size_t)bth * 512 + qqA) * 64 + e] = oA[ns][r] * ivA;
                op[((size_t)bth * 512 + qqB) * 64 + e] = oB[ns][r] * ivB;
            }
        } else {
            _Float16* op = (_Float16*)opart;
#pragma unroll
            for (int ns = 0; ns < 4; ++ns) {
                int e = ns * 16 + lc;
                op[((size_t)bth * 512 + qqA) * 64 + e] = (_Float16)(oA[ns][r] * ivA);
                op[((size_t)bth * 512 + qqB) * 64 + e] = (_Float16)(oB[ns][r] * ivB);
            }
        }
    }
}

// ---------------------------------------------------------------------------
// reduce: out[bt][q][e] = sum_h Opart[bt*8+h][q][e].  1 float4 per thread,
// 8 coalesced strided streams.  ~38MB traffic -> ~6us.
// ---------------------------------------------------------------------------
__global__ __launch_bounds__(256) void reduce_kernel(const void* __restrict__ part,
                                                     float* __restrict__ out,
                                                     int mode) {
    const int idx = blockIdx.x * 256 + threadIdx.x;  // 0..262143 (float4 units)
    const int bt = idx >> 13;                        // 8192 float4 per bt
    const int rf = idx & 8191;
    f32x4 s = (f32x4){0.f, 0.f, 0.f, 0.f};
    if (mode == 1) {
        const f32x4* p = (const f32x4*)part + (size_t)bt * 65536 + rf;
#pragma unroll
        for (int h = 0; h < 8; ++h) s += p[(size_t)h * 8192];
    } else {
        const half4* p = (const half4*)part + (size_t)bt * 65536 + rf;
#pragma unroll
        for (int h = 0; h < 8; ++h) {
            half4 v = p[(size_t)h * 8192];
            s[0] += (float)v[0]; s[1] += (float)v[1];
            s[2] += (float)v[2]; s[3] += (float)v[3];
        }
    }
    *(f32x4*)&out[(size_t)idx * 4] = s;
}

// ---------------------------------------------------------------------------
extern "C" void kernel_launch(void* const* d_in, const int* in_sizes, int n_in,
                              void* d_out, int out_size, void* d_ws, size_t ws_size,
                              hipStream_t stream) {
    const float* queries = (const float*)d_in[0];
    const float* keys    = (const float*)d_in[1];
    const float* values  = (const float*)d_in[2];
    const float* mask    = (const float*)d_in[3];
    const float* Wq      = (const float*)d_in[4];
    const float* Wk      = (const float*)d_in[5];
    const float* Wv      = (const float*)d_in[6];
    const float* w_head  = (const float*)d_in[7];
    const float* tau     = (const float*)d_in[8];
    const float* delta   = (const float*)d_in[9];

    char* ws = (char*)d_ws;
    bf16* Qw = (bf16*)(ws);                    // 16,777,216 B
    bf16* Kw = (bf16*)(ws + 16777216ull);      // 16,777,216 B
    bf16* Vt = (bf16*)(ws + 33554432ull);      // 16,777,216 B (V^T [bth][e][s])
    bf16* Wt = (bf16*)(ws + 50331648ull);      //  1,572,864 B
    bf16* Mp = (bf16*)(ws + 51904512ull);      //    524,288 B (mask, attn order)
    char* Op = ws + 52428800ull;               // partials (f32 33.5MB / f16 16.8MB)

    // mode: 1 = f32 partials, 2 = f16 partials, 0 = atomic fallback
    int mode = (ws_size >= 52428800ull + 33554432ull) ? 1
             : (ws_size >= 52428800ull + 16777216ull) ? 2 : 0;

    if (mode == 0)
        hipMemsetAsync(d_out, 0, (size_t)out_size * sizeof(float), stream);

    prep_kernel<<<dim3(8, 8, 4), 256, 0, stream>>>(Wq, Wk, Wv, mask, Wt, Mp);

    proj_kernel<<<dim3(128, 4, 3), 256, 0, stream>>>(queries, keys, values, Wt,
                                                     Qw, Kw, Vt);

    attn_kernel<<<1024, 256, 0, stream>>>(Qw, Kw, Vt, Mp, w_head, tau, delta,
                                          (float*)d_out, (void*)Op, mode);

    if (mode != 0)
        reduce_kernel<<<1024, 256, 0, stream>>>((const void*)Op, (float*)d_out,
                                                mode);
}